// Round 19
// baseline (458.627 us; speedup 1.0000x reference)
//
#include <hip/hip_runtime.h>
#include <hip/hip_bf16.h>

#define HID  2048
#define NEXP 8
#define FINT 1408
#define TM   128        // slot-tile (M)
#define BK   32
#define GU_NPAN 88
#define DN_NPAN 64
#define NG_GU (NEXP * 11 * 64)   // 5632 gateup weight tiles
#define NG_DN (NEXP * 8 * 44)    // 2816 down weight tiles

typedef __bf16 bf16_t;
typedef __bf16 bf16x8 __attribute__((ext_vector_type(8)));
typedef float  f32x4  __attribute__((ext_vector_type(4)));

#define AS1 __attribute__((address_space(1)))
#define AS3 __attribute__((address_space(3)))

__device__ __forceinline__ void gll16(const void* g, void* l) {
    __builtin_amdgcn_global_load_lds((const AS1 void*)g, (AS3 void*)l, 16, 0, 0);
}

#define VMCNT6() asm volatile("s_waitcnt vmcnt(6)" ::: "memory")
#define VMCNT0() asm volatile("s_waitcnt vmcnt(0)" ::: "memory")
#define SB0() __builtin_amdgcn_sched_barrier(0)

__device__ __forceinline__ unsigned pack2(float a, float b) {
    bf16_t x = (bf16_t)a, y = (bf16_t)b;
    unsigned short ux, uy;
    __builtin_memcpy(&ux, &x, 2);
    __builtin_memcpy(&uy, &y, 2);
    return (unsigned)ux | ((unsigned)uy << 16);
}

// ---------------- prep: router (blocks 0..RB) + cvtW (2 tiles/block, swizzled LDS) ----------------
__global__ __launch_bounds__(256) void prep_kernel(
    const float* __restrict__ x, const float* __restrict__ gw,
    int* __restrict__ cnt, int* __restrict__ topk_id, float* __restrict__ topk_w,
    bf16_t* __restrict__ xb, int T,
    const float* __restrict__ wg, const float* __restrict__ wu, const float* __restrict__ wd,
    bf16_t* __restrict__ wB, bf16_t* __restrict__ wD)
{
    const int RB = T / 4;
    __shared__ uint4 lds[256][5];   // 20 KB; rows 80B (16B-aligned)

    if ((int)blockIdx.x < RB) {
        int tid = threadIdx.x;
        int lane = tid & 63, w = tid >> 6;
        int t = blockIdx.x * 4 + w;
        if (t >= T) return;
        float acc[NEXP];
#pragma unroll
        for (int e = 0; e < NEXP; ++e) acc[e] = 0.f;
        const float* xr = x + (size_t)t * HID;
        bf16_t* xo = xb + (size_t)t * HID;
        for (int i0 = lane * 4; i0 < HID; i0 += 256) {
            float4 xv = *(const float4*)(xr + i0);
            bf16_t b4[4] = {(bf16_t)xv.x, (bf16_t)xv.y, (bf16_t)xv.z, (bf16_t)xv.w};
            *(uint2*)(xo + i0) = *(uint2*)b4;
            float xs[4] = {xv.x, xv.y, xv.z, xv.w};
#pragma unroll
            for (int u = 0; u < 4; ++u) {
                const float4* g4 = (const float4*)(gw + (size_t)(i0 + u) * NEXP);
                float4 a = g4[0], b = g4[1];
                acc[0] += xs[u] * a.x; acc[1] += xs[u] * a.y; acc[2] += xs[u] * a.z; acc[3] += xs[u] * a.w;
                acc[4] += xs[u] * b.x; acc[5] += xs[u] * b.y; acc[6] += xs[u] * b.z; acc[7] += xs[u] * b.w;
            }
        }
#pragma unroll
        for (int d = 1; d < 64; d <<= 1) {
#pragma unroll
            for (int e = 0; e < NEXP; ++e) acc[e] += __shfl_xor(acc[e], d, 64);
        }
        float mx = acc[0];
#pragma unroll
        for (int e = 1; e < NEXP; ++e) mx = fmaxf(mx, acc[e]);
        float p[NEXP]; float s = 0.f;
#pragma unroll
        for (int e = 0; e < NEXP; ++e) { p[e] = expf(acc[e] - mx); s += p[e]; }
        float inv = 1.f / s;
        int i1 = 0;
#pragma unroll
        for (int e = 1; e < NEXP; ++e) if (acc[e] > acc[i1]) i1 = e;
        int i2 = (i1 == 0) ? 1 : 0;
#pragma unroll
        for (int e = 0; e < NEXP; ++e) if (e != i1 && acc[e] > acc[i2]) i2 = e;
        if (lane == 0) {
            topk_id[t * 2 + 0] = i1; topk_id[t * 2 + 1] = i2;
            topk_w[t * 2 + 0] = p[i1] * inv; topk_w[t * 2 + 1] = p[i2] * inv;
            atomicAdd(&cnt[i1], 1); atomicAdd(&cnt[i2], 1);
        }
        return;
    }

    const int t = threadIdx.x;
    unsigned* ldsw = (unsigned*)lds;

    auto ldTile = [&](int b, float4* A4, float4* B4) {
        if (b < NG_GU) {
            int e = b / 704, rem = b - e * 704;
            int fp = rem / 64, kt = rem - fp * 64;
            int tp = t & 127;
            const float* W = (t < 128) ? wg : wu;
            const float* src = W + ((size_t)e * HID + kt * 32) * FINT + fp * 128;
#pragma unroll
            for (int r = 0; r < 4; ++r) {
                int kp = ((tp >> 4) & 7) | ((r & 1) << 3);
                int f  = ((tp & 15) | ((r >> 1) << 4)) * 4;
                const float* s0 = src + (size_t)(2 * kp) * FINT + f;
                A4[r] = *(const float4*)s0;
                B4[r] = *(const float4*)(s0 + FINT);
            }
        } else {
            int b2 = b - NG_GU;
            int e = b2 / 352, rem = b2 - e * 352;
            int hp = rem / 44, kt = rem - hp * 44;
            const float* src = wd + ((size_t)e * FINT + kt * 32) * HID + hp * 256;
            int kp = t >> 4;
#pragma unroll
            for (int r = 0; r < 4; ++r) {
                int h = ((t & 15) + 16 * r) * 4;
                const float* s0 = src + (size_t)(2 * kp) * HID + h;
                A4[r] = *(const float4*)s0;
                B4[r] = *(const float4*)(s0 + HID);
            }
        }
    };
    auto wrTile = [&](int b, float4* A4, float4* B4) {
        if (b < NG_GU) {
            int tp = t & 127;
            int rbase = (t < 128) ? 0 : 128;
#pragma unroll
            for (int r = 0; r < 4; ++r) {
                int kp = ((tp >> 4) & 7) | ((r & 1) << 3);
                int f  = ((tp & 15) | ((r >> 1) << 4)) * 4;
                unsigned v0 = pack2(A4[r].x, B4[r].x), v1 = pack2(A4[r].y, B4[r].y);
                unsigned v2 = pack2(A4[r].z, B4[r].z), v3 = pack2(A4[r].w, B4[r].w);
                int row0 = rbase + f;
                int cp = ((kp >> 2) ^ ((row0 >> 2) & 3)) * 4 + (kp & 3);
                ldsw[(row0 + 0) * 20 + cp] = v0;
                ldsw[(row0 + 1) * 20 + cp] = v1;
                ldsw[(row0 + 2) * 20 + cp] = v2;
                ldsw[(row0 + 3) * 20 + cp] = v3;
            }
        } else {
            int kp = t >> 4;
#pragma unroll
            for (int r = 0; r < 4; ++r) {
                int h = ((t & 15) + 16 * r) * 4;
                unsigned v0 = pack2(A4[r].x, B4[r].x), v1 = pack2(A4[r].y, B4[r].y);
                unsigned v2 = pack2(A4[r].z, B4[r].z), v3 = pack2(A4[r].w, B4[r].w);
                int cp = ((kp >> 2) ^ ((h >> 2) & 3)) * 4 + (kp & 3);
                ldsw[(h + 0) * 20 + cp] = v0;
                ldsw[(h + 1) * 20 + cp] = v1;
                ldsw[(h + 2) * 20 + cp] = v2;
                ldsw[(h + 3) * 20 + cp] = v3;
            }
        }
    };
    auto stTile = [&](int b) {
        bf16_t* dst16 = (b < NG_GU) ? wB + (size_t)b * 8192 + t * 32
                                    : wD + (size_t)(b - NG_GU) * 8192 + t * 32;
        int swz = ((t & 15) >> 1) & 3;
        int rx = (t >> 2) & 3;
        uint4* dst = (uint4*)dst16;
#pragma unroll
        for (int c = 0; c < 4; ++c)
            dst[c] = lds[t][(c ^ swz) ^ rx];
    };

    int bi = (int)blockIdx.x - RB;
    int b0 = bi * 2, b1 = b0 + 1;
    float4 A0[4], B0[4], A1[4], B1[4];
    ldTile(b0, A0, B0);
    ldTile(b1, A1, B1);
    wrTile(b0, A0, B0);
    __syncthreads();
    stTile(b0);
    __syncthreads();
    wrTile(b1, A1, B1);
    __syncthreads();
    stTile(b1);
}

// ---------------- offsets + per-XCD panel-major item lists ----------------
__global__ void offsets_kernel(const int* __restrict__ cnt, int* __restrict__ offs,
                               int* __restrict__ gbase, int* __restrict__ gcount,
                               int* __restrict__ dbase, int* __restrict__ dcount,
                               int* __restrict__ gu, int* __restrict__ dn)
{
    __shared__ int gc[8], dc[8];
    int tid = threadIdx.x;
    if (tid == 0) {
        int s = 0;
        for (int e = 0; e < NEXP; ++e) { offs[e] = s; s += cnt[e]; }
        offs[NEXP] = s;
    }
    if (tid < 8) {
        int c = 0;
        for (int p = tid; p < GU_NPAN; p += 8) { int e = p / 11; c += (cnt[e] + TM - 1) / TM; }
        gc[tid] = c;
    } else if (tid < 16) {
        int x = tid - 8, c = 0;
        for (int p = x; p < DN_NPAN; p += 8) { int e = p >> 3; c += (cnt[e] + TM - 1) / TM; }
        dc[x] = c;
    }
    __syncthreads();
    if (tid < 8) {
        int base = 0;
        for (int i = 0; i < tid; ++i) base += gc[i];
        gbase[tid] = base; gcount[tid] = gc[tid];
        int k = base;
        for (int p = tid; p < GU_NPAN; p += 8) {
            int e = p / 11, fp = p - e * 11;
            int nt = (cnt[e] + TM - 1) / TM;
            for (int t = 0; t < nt; ++t) gu[k++] = (e << 10) | (fp << 6) | t;
        }
    } else if (tid < 16) {
        int x = tid - 8;
        int base = 0;
        for (int i = 0; i < x; ++i) base += dc[i];
        dbase[x] = base; dcount[x] = dc[x];
        int k = base;
        for (int p = x; p < DN_NPAN; p += 8) {
            int e = p >> 3, hp = p & 7;
            int nt = (cnt[e] + TM - 1) / TM;
            for (int t = 0; t < nt; ++t) dn[k++] = (e << 10) | (hp << 6) | t;
        }
    }
}

__global__ void scatter_kernel(
    const int* __restrict__ topk_id, const int* __restrict__ offs, int* __restrict__ fill,
    int* __restrict__ tok, int* __restrict__ slot_of, int T)
{
    int t = blockIdx.x * blockDim.x + threadIdx.x;
    if (t >= T) return;
#pragma unroll
    for (int k = 0; k < 2; ++k) {
        int e = topk_id[t * 2 + k];
        int pos = atomicAdd(&fill[e], 1);
        int slot = offs[e] + pos;
        tok[slot] = t;
        slot_of[t * 2 + k] = slot;
    }
}

// ======== gate+up GEMM: 128 slots x (128f x {gate,up}) tile, 256 thr, 2 blk/CU,
//          dist-2 triple-buffer counted vmcnt(6), tiled-B contiguous staging ========
__global__ __launch_bounds__(256, 2) void gateup3_kernel(
    const bf16_t* __restrict__ xb, const bf16_t* __restrict__ wB,
    const int* __restrict__ offs, const int* __restrict__ tok,
    const int* __restrict__ gbase, const int* __restrict__ gcount, const int* __restrict__ gu,
    bf16_t* __restrict__ h_buf)
{
    __shared__ bf16_t smem[36864];   // A: 3*4096, B: 3*8192 (72 KB); epilogue reuses [0,16384)
    const int tid = threadIdx.x;
    const int lane = tid & 63, w = tid >> 6;
    const int lr = lane & 15, lg = lane >> 4;
    const int rl = lane >> 2;
    const int sw8 = ((lane & 3) ^ ((lane >> 3) & 3)) * 8;   // A-source k pre-swizzle
    const int ksw = (lg ^ ((lr >> 1) & 3)) * 8;             // read-side swizzle

    const int xcd = blockIdx.x & 7, slot = blockIdx.x >> 3;  // 88 slots per xcd
    const int icnt = gcount[xcd], ib = gbase[xcd];

    for (int ii = slot; ii < icnt; ii += 88) {
        const int it = gu[ib + ii];
        const int e = it >> 10, fp = (it >> 6) & 15, tr = it & 63;
        const int seg0 = offs[e];
        const int rbase = tr * TM;
        const int nvalid = min(offs[e + 1] - seg0 - rbase, TM);
        const int row0 = seg0 + rbase;
        const int f0 = fp * 128;

        const bf16_t* aP[2];
#pragma unroll
        for (int i = 0; i < 2; ++i) {
            int r = w * 32 + i * 16 + rl;
            int tk = tok[row0 + min(r, nvalid - 1)];
            aP[i] = xb + (size_t)tk * HID + sw8;
        }
        // tiled B: contiguous per instruction (lane-linear source)
        const bf16_t* bT = wB + (size_t)(e * 11 + fp) * 64 * 8192 + lane * 8;

        f32x4 acc[8][4];
#pragma unroll
        for (int mi = 0; mi < 8; ++mi)
#pragma unroll
            for (int ni = 0; ni < 4; ++ni) acc[mi][ni] = (f32x4){0.f, 0.f, 0.f, 0.f};

        auto STAGE = [&](int b, int kt) {
            int k0 = kt * BK;
            bf16_t* A = smem + b * 4096;
            bf16_t* B = smem + 12288 + b * 8192;
            gll16(aP[0] + k0, A + (w * 2 + 0) * 512);
            gll16(aP[1] + k0, A + (w * 2 + 1) * 512);
            const bf16_t* bk = bT + (size_t)kt * 8192;
            gll16(bk + (w * 4 + 0) * 512, B + (w * 4 + 0) * 512);
            gll16(bk + (w * 4 + 1) * 512, B + (w * 4 + 1) * 512);
            gll16(bk + (w * 4 + 2) * 512, B + (w * 4 + 2) * 512);
            gll16(bk + (w * 4 + 3) * 512, B + (w * 4 + 3) * 512);
        };
        auto COMPUTE = [&](int b) {
            const bf16_t* A = smem + b * 4096;
            const bf16_t* B = smem + 12288 + b * 8192;
            bf16x8 bfr[4];
#pragma unroll
            for (int ni = 0; ni < 4; ++ni)
                bfr[ni] = *(const bf16x8*)&B[(w * 64 + ni * 16 + lr) * BK + ksw];
#pragma unroll
            for (int mi = 0; mi < 8; ++mi) {
                bf16x8 a = *(const bf16x8*)&A[(mi * 16 + lr) * BK + ksw];
#pragma unroll
                for (int ni = 0; ni < 4; ++ni)
                    acc[mi][ni] = __builtin_amdgcn_mfma_f32_16x16x32_bf16(a, bfr[ni], acc[mi][ni], 0, 0, 0);
            }
        };

        const int NK = HID / BK;   // 64
        STAGE(0, 0); STAGE(1, 1);
        int c0 = 0, c1 = 1, c2 = 2;
        for (int kt = 0; kt < NK - 1; ++kt) {
            SB0(); VMCNT6(); __builtin_amdgcn_s_barrier(); SB0();
            if (kt + 2 < NK) STAGE(c2, kt + 2);
            SB0();
            COMPUTE(c0);
            int t = c0; c0 = c1; c1 = c2; c2 = t;
        }
        SB0(); VMCNT0(); __builtin_amdgcn_s_barrier(); SB0();
        COMPUTE(c0);
        __syncthreads();

        // epilogue: up waves park u in LDS (bf16 [128][128]), gate waves combine
        if (w >= 2) {
#pragma unroll
            for (int mi = 0; mi < 8; ++mi)
#pragma unroll
                for (int ni = 0; ni < 4; ++ni)
#pragma unroll
                    for (int rr = 0; rr < 4; ++rr) {
                        int row = mi * 16 + lg * 4 + rr;
                        int col = (w - 2) * 64 + ni * 16 + lr;
                        smem[row * 128 + col] = (bf16_t)acc[mi][ni][rr];
                    }
        }
        __syncthreads();
        if (w < 2) {
#pragma unroll
            for (int mi = 0; mi < 8; ++mi)
#pragma unroll
                for (int ni = 0; ni < 4; ++ni)
#pragma unroll
                    for (int rr = 0; rr < 4; ++rr) {
                        int row = mi * 16 + lg * 4 + rr;
                        int col = w * 64 + ni * 16 + lr;
                        float g = acc[mi][ni][rr];
                        float u = (float)smem[row * 128 + col];
                        float h = (g / (1.f + __expf(-g))) * u;
                        if (row < nvalid)
                            h_buf[(size_t)(row0 + row) * FINT + f0 + col] = (bf16_t)h;
                    }
        }
        __syncthreads();
    }
}

// ======== down GEMM: 128 slots x 256 h-cols tile, same core, tiled-B staging ========
__global__ __launch_bounds__(256, 2) void down3_kernel(
    const bf16_t* __restrict__ h_buf, const bf16_t* __restrict__ wD,
    const int* __restrict__ offs,
    const int* __restrict__ dbase, const int* __restrict__ dcount, const int* __restrict__ dn,
    bf16_t* __restrict__ y_buf)
{
    __shared__ bf16_t smem[36864];
    const int tid = threadIdx.x;
    const int lane = tid & 63, w = tid >> 6;
    const int lr = lane & 15, lg = lane >> 4;
    const int rl = lane >> 2;
    const int sw8 = ((lane & 3) ^ ((lane >> 3) & 3)) * 8;
    const int ksw = (lg ^ ((lr >> 1) & 3)) * 8;

    const int xcd = blockIdx.x & 7, slot = blockIdx.x >> 3;  // 64 slots per xcd
    const int icnt = dcount[xcd], ib = dbase[xcd];

    for (int ii = slot; ii < icnt; ii += 64) {
        const int it = dn[ib + ii];
        const int e = it >> 10, hp = (it >> 6) & 15, tr = it & 63;
        const int seg0 = offs[e];
        const int rbase = tr * TM;
        const int nvalid = min(offs[e + 1] - seg0 - rbase, TM);
        const int row0 = seg0 + rbase;
        const int h0 = hp * 256;

        const bf16_t* aP[2];
#pragma unroll
        for (int i = 0; i < 2; ++i) {
            int r = w * 32 + i * 16 + rl;
            aP[i] = h_buf + (size_t)(row0 + min(r, nvalid - 1)) * FINT + sw8;
        }
        const bf16_t* bT = wD + (size_t)(e * 8 + hp) * 44 * 8192 + lane * 8;

        f32x4 acc[8][4];
#pragma unroll
        for (int mi = 0; mi < 8; ++mi)
#pragma unroll
            for (int ni = 0; ni < 4; ++ni) acc[mi][ni] = (f32x4){0.f, 0.f, 0.f, 0.f};

        auto STAGE = [&](int b, int kt) {
            int k0 = kt * BK;
            bf16_t* A = smem + b * 4096;
            bf16_t* B = smem + 12288 + b * 8192;
            gll16(aP[0] + k0, A + (w * 2 + 0) * 512);
            gll16(aP[1] + k0, A + (w * 2 + 1) * 512);
            const bf16_t* bk = bT + (size_t)kt * 8192;
            gll16(bk + (w * 4 + 0) * 512, B + (w * 4 + 0) * 512);
            gll16(bk + (w * 4 + 1) * 512, B + (w * 4 + 1) * 512);
            gll16(bk + (w * 4 + 2) * 512, B + (w * 4 + 2) * 512);
            gll16(bk + (w * 4 + 3) * 512, B + (w * 4 + 3) * 512);
        };
        auto COMPUTE = [&](int b) {
            const bf16_t* A = smem + b * 4096;
            const bf16_t* B = smem + 12288 + b * 8192;
            bf16x8 bfr[4];
#pragma unroll
            for (int ni = 0; ni < 4; ++ni)
                bfr[ni] = *(const bf16x8*)&B[(w * 64 + ni * 16 + lr) * BK + ksw];
#pragma unroll
            for (int mi = 0; mi < 8; ++mi) {
                bf16x8 a = *(const bf16x8*)&A[(mi * 16 + lr) * BK + ksw];
#pragma unroll
                for (int ni = 0; ni < 4; ++ni)
                    acc[mi][ni] = __builtin_amdgcn_mfma_f32_16x16x32_bf16(a, bfr[ni], acc[mi][ni], 0, 0, 0);
            }
        };

        const int NK = FINT / BK;  // 44
        STAGE(0, 0); STAGE(1, 1);
        int c0 = 0, c1 = 1, c2 = 2;
        for (int kt = 0; kt < NK - 1; ++kt) {
            SB0(); VMCNT6(); __builtin_amdgcn_s_barrier(); SB0();
            if (kt + 2 < NK) STAGE(c2, kt + 2);
            SB0();
            COMPUTE(c0);
            int t = c0; c0 = c1; c1 = c2; c2 = t;
        }
        SB0(); VMCNT0(); __builtin_amdgcn_s_barrier(); SB0();
        COMPUTE(c0);

#pragma unroll
        for (int mi = 0; mi < 8; ++mi)
#pragma unroll
            for (int ni = 0; ni < 4; ++ni)
#pragma unroll
                for (int rr = 0; rr < 4; ++rr) {
                    int row = mi * 16 + lg * 4 + rr;
                    int col = w * 64 + ni * 16 + lr;
                    if (row < nvalid)
                        y_buf[(size_t)(row0 + row) * HID + h0 + col] = (bf16_t)acc[mi][ni][rr];
                }
        __syncthreads();
    }
}

// ---------------- combine: out[t] = w0*y[s0] + w1*y[s1] ----------------
__global__ __launch_bounds__(256) void combine_kernel(
    const bf16_t* __restrict__ y, const int* __restrict__ slot_of,
    const float* __restrict__ topk_w, float* __restrict__ out, int T)
{
    int t = blockIdx.x;
    int tid = threadIdx.x;
    int s0 = slot_of[t * 2], s1 = slot_of[t * 2 + 1];
    float w0 = topk_w[t * 2], w1 = topk_w[t * 2 + 1];
    const bf16x8* y0 = (const bf16x8*)(y + (size_t)s0 * HID);
    const bf16x8* y1 = (const bf16x8*)(y + (size_t)s1 * HID);
    bf16x8 v0 = y0[tid], v1 = y1[tid];
    float* op = out + (size_t)t * HID + tid * 8;
#pragma unroll
    for (int j = 0; j < 8; ++j)
        op[j] = w0 * (float)v0[j] + w1 * (float)v1[j];
}

extern "C" void kernel_launch(void* const* d_in, const int* in_sizes, int n_in,
                              void* d_out, int out_size, void* d_ws, size_t ws_size,
                              hipStream_t stream)
{
    const float* x  = (const float*)d_in[0];
    const float* gw = (const float*)d_in[1];
    const float* wg = (const float*)d_in[2];
    const float* wu = (const float*)d_in[3];
    const float* wd = (const float*)d_in[4];
    float* out = (float*)d_out;
    int T = in_sizes[0] / HID;     // 4096
    int S2 = 2 * T;

    char* base = (char*)d_ws;
    int* cnt     = (int*)base;
    int* fill    = cnt + 8;
    int* offs    = cnt + 16;
    int* gbase   = cnt + 32;
    int* gcount  = cnt + 40;
    int* dbase   = cnt + 48;
    int* dcount  = cnt + 56;
    int* gu      = cnt + 64;
    int* dnl     = cnt + 1088;
    int* topk_id = cnt + 1856;
    float* topk_w = (float*)(topk_id + S2);
    int* tok     = (int*)(topk_w + S2);
    int* slot_of = tok + S2 + 256;
    size_t small_end = (size_t)((char*)(slot_of + S2) - base);
    size_t cur = (small_end + 255) & ~(size_t)255;
    auto take = [&](size_t bytes) -> size_t {
        size_t o = cur; cur += bytes; cur = (cur + 255) & ~(size_t)255; return o;
    };
    size_t o_xb = take((size_t)T * HID * 2);
    size_t o_wB = take((size_t)NG_GU * 8192 * 2);
    size_t o_wD = take((size_t)NG_DN * 8192 * 2);
    size_t o_h  = take((size_t)(S2 + 256) * FINT * 2);
    size_t o_y  = take((size_t)(S2 + 256) * HID * 2);
    (void)ws_size;

    bf16_t* xb    = (bf16_t*)(base + o_xb);
    bf16_t* wB    = (bf16_t*)(base + o_wB);
    bf16_t* wD    = (bf16_t*)(base + o_wD);
    bf16_t* h_buf = (bf16_t*)(base + o_h);
    bf16_t* y_buf = (bf16_t*)(base + o_y);

    hipMemsetAsync(base, 0, 64, stream);   // cnt + fill

    int RB = T / 4;                                    // 1024 router blocks
    int gridPrep = RB + (NG_GU + NG_DN) / 2;           // 1024 + 4224
    prep_kernel<<<gridPrep, 256, 0, stream>>>(x, gw, cnt, topk_id, topk_w, xb, T,
                                              wg, wu, wd, wB, wD);
    offsets_kernel<<<1, 64, 0, stream>>>(cnt, offs, gbase, gcount, dbase, dcount, gu, dnl);
    scatter_kernel<<<(T + 255) / 256, 256, 0, stream>>>(topk_id, offs, fill, tok, slot_of, T);

    gateup3_kernel<<<704, 256, 0, stream>>>(xb, wB, offs, tok, gbase, gcount, gu, h_buf);
    down3_kernel<<<512, 256, 0, stream>>>(h_buf, wD, offs, dbase, dcount, dnl, y_buf);
    combine_kernel<<<T, 256, 0, stream>>>(y_buf, slot_of, topk_w, out, T);
}

// Round 21
// 438.499 us; speedup vs baseline: 1.0459x; 1.0459x over previous
//
#include <hip/hip_runtime.h>
#include <hip/hip_bf16.h>

#define HID  2048
#define NEXP 8
#define FINT 1408
#define TM   128        // slot-tile (M)
#define BK   32
#define GU_NPAN 88
#define DN_NPAN 64
#define NG_GU (NEXP * 11 * 64)   // 5632 gateup weight tiles
#define NG_DN (NEXP * 8 * 44)    // 2816 down weight tiles

typedef __bf16 bf16_t;
typedef __bf16 bf16x8 __attribute__((ext_vector_type(8)));
typedef float  f32x4  __attribute__((ext_vector_type(4)));

#define AS1 __attribute__((address_space(1)))
#define AS3 __attribute__((address_space(3)))

__device__ __forceinline__ void gll16(const void* g, void* l) {
    __builtin_amdgcn_global_load_lds((const AS1 void*)g, (AS3 void*)l, 16, 0, 0);
}

#define VMCNT6() asm volatile("s_waitcnt vmcnt(6)" ::: "memory")
#define VMCNT0() asm volatile("s_waitcnt vmcnt(0)" ::: "memory")
#define SB0() __builtin_amdgcn_sched_barrier(0)

__device__ __forceinline__ unsigned pack2(float a, float b) {
    bf16_t x = (bf16_t)a, y = (bf16_t)b;
    unsigned short ux, uy;
    __builtin_memcpy(&ux, &x, 2);
    __builtin_memcpy(&uy, &y, 2);
    return (unsigned)ux | ((unsigned)uy << 16);
}

// ---------------- prep: router (blocks 0..RB) + cvtW tiled weight conversion ----------------
__global__ __launch_bounds__(256) void prep_kernel(
    const float* __restrict__ x, const float* __restrict__ gw,
    int* __restrict__ cnt, int* __restrict__ topk_id, float* __restrict__ topk_w,
    bf16_t* __restrict__ xb, int T,
    const float* __restrict__ wg, const float* __restrict__ wu, const float* __restrict__ wd,
    bf16_t* __restrict__ wB, bf16_t* __restrict__ wD)
{
    const int RB = T / 4;
    __shared__ unsigned lds[256][20];

    if ((int)blockIdx.x < RB) {
        int tid = threadIdx.x;
        int lane = tid & 63, w = tid >> 6;
        int t = blockIdx.x * 4 + w;
        if (t >= T) return;
        float acc[NEXP];
#pragma unroll
        for (int e = 0; e < NEXP; ++e) acc[e] = 0.f;
        const float* xr = x + (size_t)t * HID;
        bf16_t* xo = xb + (size_t)t * HID;
        for (int i0 = lane * 4; i0 < HID; i0 += 256) {
            float4 xv = *(const float4*)(xr + i0);
            bf16_t b4[4] = {(bf16_t)xv.x, (bf16_t)xv.y, (bf16_t)xv.z, (bf16_t)xv.w};
            *(uint2*)(xo + i0) = *(uint2*)b4;
            float xs[4] = {xv.x, xv.y, xv.z, xv.w};
#pragma unroll
            for (int u = 0; u < 4; ++u) {
                const float4* g4 = (const float4*)(gw + (size_t)(i0 + u) * NEXP);
                float4 a = g4[0], b = g4[1];
                acc[0] += xs[u] * a.x; acc[1] += xs[u] * a.y; acc[2] += xs[u] * a.z; acc[3] += xs[u] * a.w;
                acc[4] += xs[u] * b.x; acc[5] += xs[u] * b.y; acc[6] += xs[u] * b.z; acc[7] += xs[u] * b.w;
            }
        }
#pragma unroll
        for (int d = 1; d < 64; d <<= 1) {
#pragma unroll
            for (int e = 0; e < NEXP; ++e) acc[e] += __shfl_xor(acc[e], d, 64);
        }
        float mx = acc[0];
#pragma unroll
        for (int e = 1; e < NEXP; ++e) mx = fmaxf(mx, acc[e]);
        float p[NEXP]; float s = 0.f;
#pragma unroll
        for (int e = 0; e < NEXP; ++e) { p[e] = expf(acc[e] - mx); s += p[e]; }
        float inv = 1.f / s;
        int i1 = 0;
#pragma unroll
        for (int e = 1; e < NEXP; ++e) if (acc[e] > acc[i1]) i1 = e;
        int i2 = (i1 == 0) ? 1 : 0;
#pragma unroll
        for (int e = 0; e < NEXP; ++e) if (e != i1 && acc[e] > acc[i2]) i2 = e;
        if (lane == 0) {
            topk_id[t * 2 + 0] = i1; topk_id[t * 2 + 1] = i2;
            topk_w[t * 2 + 0] = p[i1] * inv; topk_w[t * 2 + 1] = p[i2] * inv;
            atomicAdd(&cnt[i1], 1); atomicAdd(&cnt[i2], 1);
        }
        return;
    }

    int b = blockIdx.x - RB;
    int t = threadIdx.x;
    bf16_t* dst16;

    if (b < NG_GU) {
        int e = b / 704, rem = b - e * 704;
        int fp = rem / 64, kt = rem - fp * 64;
        int tp = t & 127;
        const float* W = (t < 128) ? wg : wu;
        int rbase = (t < 128) ? 0 : 128;
        const float* src = W + ((size_t)e * HID + kt * 32) * FINT + fp * 128;
#pragma unroll
        for (int r = 0; r < 4; ++r) {
            int kp = ((tp >> 4) & 7) | ((r & 1) << 3);
            int f  = ((tp & 15) | ((r >> 1) << 4)) * 4;
            const float* s0 = src + (size_t)(2 * kp) * FINT + f;
            float4 a  = *(const float4*)s0;
            float4 bb = *(const float4*)(s0 + FINT);
            lds[rbase + f + 0][kp] = pack2(a.x, bb.x);
            lds[rbase + f + 1][kp] = pack2(a.y, bb.y);
            lds[rbase + f + 2][kp] = pack2(a.z, bb.z);
            lds[rbase + f + 3][kp] = pack2(a.w, bb.w);
        }
        dst16 = wB + (size_t)b * 8192 + t * 32;
    } else {
        int b2 = b - NG_GU;
        int e = b2 / 352, rem = b2 - e * 352;
        int hp = rem / 44, kt = rem - hp * 44;
        const float* src = wd + ((size_t)e * FINT + kt * 32) * HID + hp * 256;
        int kp = t >> 4;
#pragma unroll
        for (int r = 0; r < 4; ++r) {
            int h = ((t & 15) + 16 * r) * 4;
            const float* s0 = src + (size_t)(2 * kp) * HID + h;
            float4 a  = *(const float4*)s0;
            float4 bb = *(const float4*)(s0 + HID);
            lds[h + 0][kp] = pack2(a.x, bb.x);
            lds[h + 1][kp] = pack2(a.y, bb.y);
            lds[h + 2][kp] = pack2(a.z, bb.z);
            lds[h + 3][kp] = pack2(a.w, bb.w);
        }
        dst16 = wD + (size_t)b2 * 8192 + t * 32;
    }
    __syncthreads();

    int swz = ((t & 15) >> 1) & 3;
    uint4* dst = (uint4*)dst16;
#pragma unroll
    for (int c = 0; c < 4; ++c)
        dst[c] = *(const uint4*)&lds[t][(c ^ swz) * 4];
}

// ---------------- offsets + per-XCD panel-major item lists ----------------
__global__ void offsets_kernel(const int* __restrict__ cnt, int* __restrict__ offs,
                               int* __restrict__ gbase, int* __restrict__ gcount,
                               int* __restrict__ dbase, int* __restrict__ dcount,
                               int* __restrict__ gu, int* __restrict__ dn)
{
    __shared__ int gc[8], dc[8];
    int tid = threadIdx.x;
    if (tid == 0) {
        int s = 0;
        for (int e = 0; e < NEXP; ++e) { offs[e] = s; s += cnt[e]; }
        offs[NEXP] = s;
    }
    if (tid < 8) {
        int c = 0;
        for (int p = tid; p < GU_NPAN; p += 8) { int e = p / 11; c += (cnt[e] + TM - 1) / TM; }
        gc[tid] = c;
    } else if (tid < 16) {
        int x = tid - 8, c = 0;
        for (int p = x; p < DN_NPAN; p += 8) { int e = p >> 3; c += (cnt[e] + TM - 1) / TM; }
        dc[x] = c;
    }
    __syncthreads();
    if (tid < 8) {
        int base = 0;
        for (int i = 0; i < tid; ++i) base += gc[i];
        gbase[tid] = base; gcount[tid] = gc[tid];
        int k = base;
        for (int p = tid; p < GU_NPAN; p += 8) {
            int e = p / 11, fp = p - e * 11;
            int nt = (cnt[e] + TM - 1) / TM;
            for (int t = 0; t < nt; ++t) gu[k++] = (e << 10) | (fp << 6) | t;
        }
    } else if (tid < 16) {
        int x = tid - 8;
        int base = 0;
        for (int i = 0; i < x; ++i) base += dc[i];
        dbase[x] = base; dcount[x] = dc[x];
        int k = base;
        for (int p = x; p < DN_NPAN; p += 8) {
            int e = p >> 3, hp = p & 7;
            int nt = (cnt[e] + TM - 1) / TM;
            for (int t = 0; t < nt; ++t) dn[k++] = (e << 10) | (hp << 6) | t;
        }
    }
}

__global__ void scatter_kernel(
    const int* __restrict__ topk_id, const int* __restrict__ offs, int* __restrict__ fill,
    int* __restrict__ tok, int* __restrict__ slot_of, int T)
{
    int t = blockIdx.x * blockDim.x + threadIdx.x;
    if (t >= T) return;
#pragma unroll
    for (int k = 0; k < 2; ++k) {
        int e = topk_id[t * 2 + k];
        int pos = atomicAdd(&fill[e], 1);
        int slot = offs[e] + pos;
        tok[slot] = t;
        slot_of[t * 2 + k] = slot;
    }
}

// ======== gate+up GEMM: 128 slots x (128f x {gate,up}) tile, 256 thr, 2 blk/CU,
//          dist-2 triple-buffer counted vmcnt(6), tiled-B contiguous staging ========
__global__ __launch_bounds__(256, 2) void gateup3_kernel(
    const bf16_t* __restrict__ xb, const bf16_t* __restrict__ wB,
    const int* __restrict__ offs, const int* __restrict__ tok,
    const int* __restrict__ gbase, const int* __restrict__ gcount, const int* __restrict__ gu,
    bf16_t* __restrict__ h_buf)
{
    __shared__ bf16_t smem[36864];   // A: 3*4096, B: 3*8192 (72 KB); epilogue reuses [0,16384)
    const int tid = threadIdx.x;
    const int lane = tid & 63, w = tid >> 6;
    const int lr = lane & 15, lg = lane >> 4;
    const int rl = lane >> 2;
    const int sw8 = ((lane & 3) ^ ((lane >> 3) & 3)) * 8;   // A-source k pre-swizzle
    const int ksw = (lg ^ ((lr >> 1) & 3)) * 8;             // read-side swizzle

    const int xcd = blockIdx.x & 7, slot = blockIdx.x >> 3;  // 88 slots per xcd
    const int icnt = gcount[xcd], ib = gbase[xcd];

    for (int ii = slot; ii < icnt; ii += 88) {
        const int it = gu[ib + ii];
        const int e = it >> 10, fp = (it >> 6) & 15, tr = it & 63;
        const int seg0 = offs[e];
        const int rbase = tr * TM;
        const int nvalid = min(offs[e + 1] - seg0 - rbase, TM);
        const int row0 = seg0 + rbase;
        const int f0 = fp * 128;

        const bf16_t* aP[2];
#pragma unroll
        for (int i = 0; i < 2; ++i) {
            int r = w * 32 + i * 16 + rl;
            int tk = tok[row0 + min(r, nvalid - 1)];
            aP[i] = xb + (size_t)tk * HID + sw8;
        }
        // tiled B: contiguous per instruction (lane-linear source)
        const bf16_t* bT = wB + (size_t)(e * 11 + fp) * 64 * 8192 + lane * 8;

        f32x4 acc[8][4];
#pragma unroll
        for (int mi = 0; mi < 8; ++mi)
#pragma unroll
            for (int ni = 0; ni < 4; ++ni) acc[mi][ni] = (f32x4){0.f, 0.f, 0.f, 0.f};

        auto STAGE = [&](int b, int kt) {
            int k0 = kt * BK;
            bf16_t* A = smem + b * 4096;
            bf16_t* B = smem + 12288 + b * 8192;
            gll16(aP[0] + k0, A + (w * 2 + 0) * 512);
            gll16(aP[1] + k0, A + (w * 2 + 1) * 512);
            const bf16_t* bk = bT + (size_t)kt * 8192;
            gll16(bk + (w * 4 + 0) * 512, B + (w * 4 + 0) * 512);
            gll16(bk + (w * 4 + 1) * 512, B + (w * 4 + 1) * 512);
            gll16(bk + (w * 4 + 2) * 512, B + (w * 4 + 2) * 512);
            gll16(bk + (w * 4 + 3) * 512, B + (w * 4 + 3) * 512);
        };
        auto COMPUTE = [&](int b) {
            const bf16_t* A = smem + b * 4096;
            const bf16_t* B = smem + 12288 + b * 8192;
            bf16x8 bfr[4];
#pragma unroll
            for (int ni = 0; ni < 4; ++ni)
                bfr[ni] = *(const bf16x8*)&B[(w * 64 + ni * 16 + lr) * BK + ksw];
#pragma unroll
            for (int mi = 0; mi < 8; ++mi) {
                bf16x8 a = *(const bf16x8*)&A[(mi * 16 + lr) * BK + ksw];
#pragma unroll
                for (int ni = 0; ni < 4; ++ni)
                    acc[mi][ni] = __builtin_amdgcn_mfma_f32_16x16x32_bf16(a, bfr[ni], acc[mi][ni], 0, 0, 0);
            }
        };

        const int NK = HID / BK;   // 64
        STAGE(0, 0); STAGE(1, 1);
        int c0 = 0, c1 = 1, c2 = 2;
        for (int kt = 0; kt < NK - 1; ++kt) {
            SB0(); VMCNT6(); __builtin_amdgcn_s_barrier(); SB0();
            if (kt + 2 < NK) STAGE(c2, kt + 2);
            SB0();
            COMPUTE(c0);
            int t = c0; c0 = c1; c1 = c2; c2 = t;
        }
        SB0(); VMCNT0(); __builtin_amdgcn_s_barrier(); SB0();
        COMPUTE(c0);
        __syncthreads();

        // epilogue: up waves park u in LDS (bf16 [128][128]), gate waves combine
        if (w >= 2) {
#pragma unroll
            for (int mi = 0; mi < 8; ++mi)
#pragma unroll
                for (int ni = 0; ni < 4; ++ni)
#pragma unroll
                    for (int rr = 0; rr < 4; ++rr) {
                        int row = mi * 16 + lg * 4 + rr;
                        int col = (w - 2) * 64 + ni * 16 + lr;
                        smem[row * 128 + col] = (bf16_t)acc[mi][ni][rr];
                    }
        }
        __syncthreads();
        if (w < 2) {
#pragma unroll
            for (int mi = 0; mi < 8; ++mi)
#pragma unroll
                for (int ni = 0; ni < 4; ++ni)
#pragma unroll
                    for (int rr = 0; rr < 4; ++rr) {
                        int row = mi * 16 + lg * 4 + rr;
                        int col = w * 64 + ni * 16 + lr;
                        float g = acc[mi][ni][rr];
                        float u = (float)smem[row * 128 + col];
                        float h = (g / (1.f + __expf(-g))) * u;
                        if (row < nvalid)
                            h_buf[(size_t)(row0 + row) * FINT + f0 + col] = (bf16_t)h;
                    }
        }
        __syncthreads();
    }
}

// ======== down GEMM: 128 slots x 256 h-cols tile, same core, tiled-B staging ========
__global__ __launch_bounds__(256, 2) void down3_kernel(
    const bf16_t* __restrict__ h_buf, const bf16_t* __restrict__ wD,
    const int* __restrict__ offs,
    const int* __restrict__ dbase, const int* __restrict__ dcount, const int* __restrict__ dn,
    bf16_t* __restrict__ y_buf)
{
    __shared__ bf16_t smem[36864];
    const int tid = threadIdx.x;
    const int lane = tid & 63, w = tid >> 6;
    const int lr = lane & 15, lg = lane >> 4;
    const int rl = lane >> 2;
    const int sw8 = ((lane & 3) ^ ((lane >> 3) & 3)) * 8;
    const int ksw = (lg ^ ((lr >> 1) & 3)) * 8;

    const int xcd = blockIdx.x & 7, slot = blockIdx.x >> 3;  // 64 slots per xcd
    const int icnt = dcount[xcd], ib = dbase[xcd];

    for (int ii = slot; ii < icnt; ii += 64) {
        const int it = dn[ib + ii];
        const int e = it >> 10, hp = (it >> 6) & 15, tr = it & 63;
        const int seg0 = offs[e];
        const int rbase = tr * TM;
        const int nvalid = min(offs[e + 1] - seg0 - rbase, TM);
        const int row0 = seg0 + rbase;
        const int h0 = hp * 256;

        const bf16_t* aP[2];
#pragma unroll
        for (int i = 0; i < 2; ++i) {
            int r = w * 32 + i * 16 + rl;
            aP[i] = h_buf + (size_t)(row0 + min(r, nvalid - 1)) * FINT + sw8;
        }
        const bf16_t* bT = wD + (size_t)(e * 8 + hp) * 44 * 8192 + lane * 8;

        f32x4 acc[8][4];
#pragma unroll
        for (int mi = 0; mi < 8; ++mi)
#pragma unroll
            for (int ni = 0; ni < 4; ++ni) acc[mi][ni] = (f32x4){0.f, 0.f, 0.f, 0.f};

        auto STAGE = [&](int b, int kt) {
            int k0 = kt * BK;
            bf16_t* A = smem + b * 4096;
            bf16_t* B = smem + 12288 + b * 8192;
            gll16(aP[0] + k0, A + (w * 2 + 0) * 512);
            gll16(aP[1] + k0, A + (w * 2 + 1) * 512);
            const bf16_t* bk = bT + (size_t)kt * 8192;
            gll16(bk + (w * 4 + 0) * 512, B + (w * 4 + 0) * 512);
            gll16(bk + (w * 4 + 1) * 512, B + (w * 4 + 1) * 512);
            gll16(bk + (w * 4 + 2) * 512, B + (w * 4 + 2) * 512);
            gll16(bk + (w * 4 + 3) * 512, B + (w * 4 + 3) * 512);
        };
        auto COMPUTE = [&](int b) {
            const bf16_t* A = smem + b * 4096;
            const bf16_t* B = smem + 12288 + b * 8192;
            bf16x8 bfr[4];
#pragma unroll
            for (int ni = 0; ni < 4; ++ni)
                bfr[ni] = *(const bf16x8*)&B[(w * 64 + ni * 16 + lr) * BK + ksw];
#pragma unroll
            for (int mi = 0; mi < 8; ++mi) {
                bf16x8 a = *(const bf16x8*)&A[(mi * 16 + lr) * BK + ksw];
#pragma unroll
                for (int ni = 0; ni < 4; ++ni)
                    acc[mi][ni] = __builtin_amdgcn_mfma_f32_16x16x32_bf16(a, bfr[ni], acc[mi][ni], 0, 0, 0);
            }
        };

        const int NK = FINT / BK;  // 44
        STAGE(0, 0); STAGE(1, 1);
        int c0 = 0, c1 = 1, c2 = 2;
        for (int kt = 0; kt < NK - 1; ++kt) {
            SB0(); VMCNT6(); __builtin_amdgcn_s_barrier(); SB0();
            if (kt + 2 < NK) STAGE(c2, kt + 2);
            SB0();
            COMPUTE(c0);
            int t = c0; c0 = c1; c1 = c2; c2 = t;
        }
        SB0(); VMCNT0(); __builtin_amdgcn_s_barrier(); SB0();
        COMPUTE(c0);

#pragma unroll
        for (int mi = 0; mi < 8; ++mi)
#pragma unroll
            for (int ni = 0; ni < 4; ++ni)
#pragma unroll
                for (int rr = 0; rr < 4; ++rr) {
                    int row = mi * 16 + lg * 4 + rr;
                    int col = w * 64 + ni * 16 + lr;
                    if (row < nvalid)
                        y_buf[(size_t)(row0 + row) * HID + h0 + col] = (bf16_t)acc[mi][ni][rr];
                }
        __syncthreads();
    }
}

// ---------------- combine: out[t] = w0*y[s0] + w1*y[s1] ----------------
__global__ __launch_bounds__(256) void combine_kernel(
    const bf16_t* __restrict__ y, const int* __restrict__ slot_of,
    const float* __restrict__ topk_w, float* __restrict__ out, int T)
{
    int t = blockIdx.x;
    int tid = threadIdx.x;
    int s0 = slot_of[t * 2], s1 = slot_of[t * 2 + 1];
    float w0 = topk_w[t * 2], w1 = topk_w[t * 2 + 1];
    const bf16x8* y0 = (const bf16x8*)(y + (size_t)s0 * HID);
    const bf16x8* y1 = (const bf16x8*)(y + (size_t)s1 * HID);
    bf16x8 v0 = y0[tid], v1 = y1[tid];
    float* op = out + (size_t)t * HID + tid * 8;
#pragma unroll
    for (int j = 0; j < 8; ++j)
        op[j] = w0 * (float)v0[j] + w1 * (float)v1[j];
}

extern "C" void kernel_launch(void* const* d_in, const int* in_sizes, int n_in,
                              void* d_out, int out_size, void* d_ws, size_t ws_size,
                              hipStream_t stream)
{
    const float* x  = (const float*)d_in[0];
    const float* gw = (const float*)d_in[1];
    const float* wg = (const float*)d_in[2];
    const float* wu = (const float*)d_in[3];
    const float* wd = (const float*)d_in[4];
    float* out = (float*)d_out;
    int T = in_sizes[0] / HID;     // 4096
    int S2 = 2 * T;

    char* base = (char*)d_ws;
    int* cnt     = (int*)base;
    int* fill    = cnt + 8;
    int* offs    = cnt + 16;
    int* gbase   = cnt + 32;
    int* gcount  = cnt + 40;
    int* dbase   = cnt + 48;
    int* dcount  = cnt + 56;
    int* gu      = cnt + 64;
    int* dnl     = cnt + 1088;
    int* topk_id = cnt + 1856;
    float* topk_w = (float*)(topk_id + S2);
    int* tok     = (int*)(topk_w + S2);
    int* slot_of = tok + S2 + 256;
    size_t small_end = (size_t)((char*)(slot_of + S2) - base);
    size_t cur = (small_end + 255) & ~(size_t)255;
    auto take = [&](size_t bytes) -> size_t {
        size_t o = cur; cur += bytes; cur = (cur + 255) & ~(size_t)255; return o;
    };
    size_t o_xb = take((size_t)T * HID * 2);
    size_t o_wB = take((size_t)NG_GU * 8192 * 2);
    size_t o_wD = take((size_t)NG_DN * 8192 * 2);
    size_t o_h  = take((size_t)(S2 + 256) * FINT * 2);
    size_t o_y  = take((size_t)(S2 + 256) * HID * 2);
    (void)ws_size;

    bf16_t* xb    = (bf16_t*)(base + o_xb);
    bf16_t* wB    = (bf16_t*)(base + o_wB);
    bf16_t* wD    = (bf16_t*)(base + o_wD);
    bf16_t* h_buf = (bf16_t*)(base + o_h);
    bf16_t* y_buf = (bf16_t*)(base + o_y);

    hipMemsetAsync(base, 0, 64, stream);   // cnt + fill

    int RB = T / 4;                               // 1024 router blocks
    int gridPrep = RB + NG_GU + NG_DN;            // 1024 + 8448
    prep_kernel<<<gridPrep, 256, 0, stream>>>(x, gw, cnt, topk_id, topk_w, xb, T,
                                              wg, wu, wd, wB, wD);
    offsets_kernel<<<1, 64, 0, stream>>>(cnt, offs, gbase, gcount, dbase, dcount, gu, dnl);
    scatter_kernel<<<(T + 255) / 256, 256, 0, stream>>>(topk_id, offs, fill, tok, slot_of, T);

    gateup3_kernel<<<704, 256, 0, stream>>>(xb, wB, offs, tok, gbase, gcount, gu, h_buf);
    down3_kernel<<<512, 256, 0, stream>>>(h_buf, wD, offs, dbase, dcount, dnl, y_buf);
    combine_kernel<<<T, 256, 0, stream>>>(y_buf, slot_of, topk_w, out, T);
}

// Round 22
// 416.637 us; speedup vs baseline: 1.1008x; 1.0525x over previous
//
#include <hip/hip_runtime.h>
#include <hip/hip_bf16.h>

#define HID  2048
#define NEXP 8
#define FINT 1408
#define TM   128        // slot-tile (M)
#define BK   32
#define GU_NPAN 88
#define DN_NPAN 64
#define NG_GU (NEXP * 11 * 64)   // 5632 gateup weight tiles
#define NG_DN (NEXP * 8 * 44)    // 2816 down weight tiles
#define GU_GRID 704              // gateup GEMM blocks (88 slots x 8 xcd)

typedef __bf16 bf16_t;
typedef __bf16 bf16x8 __attribute__((ext_vector_type(8)));
typedef float  f32x4  __attribute__((ext_vector_type(4)));

#define AS1 __attribute__((address_space(1)))
#define AS3 __attribute__((address_space(3)))

__device__ __forceinline__ void gll16(const void* g, void* l) {
    __builtin_amdgcn_global_load_lds((const AS1 void*)g, (AS3 void*)l, 16, 0, 0);
}

#define VMCNT6() asm volatile("s_waitcnt vmcnt(6)" ::: "memory")
#define VMCNT0() asm volatile("s_waitcnt vmcnt(0)" ::: "memory")
#define SB0() __builtin_amdgcn_sched_barrier(0)

__device__ __forceinline__ unsigned pack2(float a, float b) {
    bf16_t x = (bf16_t)a, y = (bf16_t)b;
    unsigned short ux, uy;
    __builtin_memcpy(&ux, &x, 2);
    __builtin_memcpy(&uy, &y, 2);
    return (unsigned)ux | ((unsigned)uy << 16);
}

// ---------------- prep1: router (blocks 0..RB) + cvtGU tiled weight conversion ----------------
__global__ __launch_bounds__(256) void prep_kernel(
    const float* __restrict__ x, const float* __restrict__ gw,
    int* __restrict__ cnt, int* __restrict__ topk_id, float* __restrict__ topk_w,
    bf16_t* __restrict__ xb, int T,
    const float* __restrict__ wg, const float* __restrict__ wu,
    bf16_t* __restrict__ wB)
{
    const int RB = T / 4;
    __shared__ unsigned lds[256][20];

    if ((int)blockIdx.x < RB) {
        int tid = threadIdx.x;
        int lane = tid & 63, w = tid >> 6;
        int t = blockIdx.x * 4 + w;
        if (t >= T) return;
        float acc[NEXP];
#pragma unroll
        for (int e = 0; e < NEXP; ++e) acc[e] = 0.f;
        const float* xr = x + (size_t)t * HID;
        bf16_t* xo = xb + (size_t)t * HID;
        for (int i0 = lane * 4; i0 < HID; i0 += 256) {
            float4 xv = *(const float4*)(xr + i0);
            bf16_t b4[4] = {(bf16_t)xv.x, (bf16_t)xv.y, (bf16_t)xv.z, (bf16_t)xv.w};
            *(uint2*)(xo + i0) = *(uint2*)b4;
            float xs[4] = {xv.x, xv.y, xv.z, xv.w};
#pragma unroll
            for (int u = 0; u < 4; ++u) {
                const float4* g4 = (const float4*)(gw + (size_t)(i0 + u) * NEXP);
                float4 a = g4[0], b = g4[1];
                acc[0] += xs[u] * a.x; acc[1] += xs[u] * a.y; acc[2] += xs[u] * a.z; acc[3] += xs[u] * a.w;
                acc[4] += xs[u] * b.x; acc[5] += xs[u] * b.y; acc[6] += xs[u] * b.z; acc[7] += xs[u] * b.w;
            }
        }
#pragma unroll
        for (int d = 1; d < 64; d <<= 1) {
#pragma unroll
            for (int e = 0; e < NEXP; ++e) acc[e] += __shfl_xor(acc[e], d, 64);
        }
        float mx = acc[0];
#pragma unroll
        for (int e = 1; e < NEXP; ++e) mx = fmaxf(mx, acc[e]);
        float p[NEXP]; float s = 0.f;
#pragma unroll
        for (int e = 0; e < NEXP; ++e) { p[e] = expf(acc[e] - mx); s += p[e]; }
        float inv = 1.f / s;
        int i1 = 0;
#pragma unroll
        for (int e = 1; e < NEXP; ++e) if (acc[e] > acc[i1]) i1 = e;
        int i2 = (i1 == 0) ? 1 : 0;
#pragma unroll
        for (int e = 0; e < NEXP; ++e) if (e != i1 && acc[e] > acc[i2]) i2 = e;
        if (lane == 0) {
            topk_id[t * 2 + 0] = i1; topk_id[t * 2 + 1] = i2;
            topk_w[t * 2 + 0] = p[i1] * inv; topk_w[t * 2 + 1] = p[i2] * inv;
            atomicAdd(&cnt[i1], 1); atomicAdd(&cnt[i2], 1);
        }
        return;
    }

    int b = blockIdx.x - RB;     // [0, NG_GU)
    int t = threadIdx.x;

    int e = b / 704, rem = b - e * 704;
    int fp = rem / 64, kt = rem - fp * 64;
    int tp = t & 127;
    const float* W = (t < 128) ? wg : wu;
    int rbase = (t < 128) ? 0 : 128;
    const float* src = W + ((size_t)e * HID + kt * 32) * FINT + fp * 128;
#pragma unroll
    for (int r = 0; r < 4; ++r) {
        int kp = ((tp >> 4) & 7) | ((r & 1) << 3);
        int f  = ((tp & 15) | ((r >> 1) << 4)) * 4;
        const float* s0 = src + (size_t)(2 * kp) * FINT + f;
        float4 a  = *(const float4*)s0;
        float4 bb = *(const float4*)(s0 + FINT);
        lds[rbase + f + 0][kp] = pack2(a.x, bb.x);
        lds[rbase + f + 1][kp] = pack2(a.y, bb.y);
        lds[rbase + f + 2][kp] = pack2(a.z, bb.z);
        lds[rbase + f + 3][kp] = pack2(a.w, bb.w);
    }
    __syncthreads();

    int swz = ((t & 15) >> 1) & 3;
    uint4* dst = (uint4*)(wB + (size_t)b * 8192 + t * 32);
#pragma unroll
    for (int c = 0; c < 4; ++c)
        dst[c] = *(const uint4*)&lds[t][(c ^ swz) * 4];
}

// ---------------- offsets + per-XCD panel-major item lists ----------------
__global__ void offsets_kernel(const int* __restrict__ cnt, int* __restrict__ offs,
                               int* __restrict__ gbase, int* __restrict__ gcount,
                               int* __restrict__ dbase, int* __restrict__ dcount,
                               int* __restrict__ gu, int* __restrict__ dn)
{
    __shared__ int gc[8], dc[8];
    int tid = threadIdx.x;
    if (tid == 0) {
        int s = 0;
        for (int e = 0; e < NEXP; ++e) { offs[e] = s; s += cnt[e]; }
        offs[NEXP] = s;
    }
    if (tid < 8) {
        int c = 0;
        for (int p = tid; p < GU_NPAN; p += 8) { int e = p / 11; c += (cnt[e] + TM - 1) / TM; }
        gc[tid] = c;
    } else if (tid < 16) {
        int x = tid - 8, c = 0;
        for (int p = x; p < DN_NPAN; p += 8) { int e = p >> 3; c += (cnt[e] + TM - 1) / TM; }
        dc[x] = c;
    }
    __syncthreads();
    if (tid < 8) {
        int base = 0;
        for (int i = 0; i < tid; ++i) base += gc[i];
        gbase[tid] = base; gcount[tid] = gc[tid];
        int k = base;
        for (int p = tid; p < GU_NPAN; p += 8) {
            int e = p / 11, fp = p - e * 11;
            int nt = (cnt[e] + TM - 1) / TM;
            for (int t = 0; t < nt; ++t) gu[k++] = (e << 10) | (fp << 6) | t;
        }
    } else if (tid < 16) {
        int x = tid - 8;
        int base = 0;
        for (int i = 0; i < x; ++i) base += dc[i];
        dbase[x] = base; dcount[x] = dc[x];
        int k = base;
        for (int p = x; p < DN_NPAN; p += 8) {
            int e = p >> 3, hp = p & 7;
            int nt = (cnt[e] + TM - 1) / TM;
            for (int t = 0; t < nt; ++t) dn[k++] = (e << 10) | (hp << 6) | t;
        }
    }
}

__global__ void scatter_kernel(
    const int* __restrict__ topk_id, const int* __restrict__ offs, int* __restrict__ fill,
    int* __restrict__ tok, int* __restrict__ slot_of, int T)
{
    int t = blockIdx.x * blockDim.x + threadIdx.x;
    if (t >= T) return;
#pragma unroll
    for (int k = 0; k < 2; ++k) {
        int e = topk_id[t * 2 + k];
        int pos = atomicAdd(&fill[e], 1);
        int slot = offs[e] + pos;
        tok[slot] = t;
        slot_of[t * 2 + k] = slot;
    }
}

// ======== FUSED: gate+up GEMM (blocks < GU_GRID) + cvtDN weight conversion (rest) ========
__global__ __launch_bounds__(256, 2) void gateup3_kernel(
    const bf16_t* __restrict__ xb, const bf16_t* __restrict__ wB,
    const int* __restrict__ offs, const int* __restrict__ tok,
    const int* __restrict__ gbase, const int* __restrict__ gcount, const int* __restrict__ gu,
    bf16_t* __restrict__ h_buf,
    const float* __restrict__ wd, bf16_t* __restrict__ wD)
{
    __shared__ bf16_t smem[36864];   // GEMM: A 3*4096 | B 3*8192 (72 KB); cvt aliases 20 KB
    const int tid = threadIdx.x;

    if ((int)blockIdx.x >= GU_GRID) {
        // ---- cvtDN tile (identical to verified prep body) ----
        unsigned (*lds)[20] = (unsigned(*)[20])smem;
        int b2 = (int)blockIdx.x - GU_GRID;      // [0, NG_DN)
        int t = tid;
        int e = b2 / 352, rem = b2 - e * 352;
        int hp = rem / 44, kt = rem - hp * 44;
        const float* src = wd + ((size_t)e * FINT + kt * 32) * HID + hp * 256;
        int kp = t >> 4;
#pragma unroll
        for (int r = 0; r < 4; ++r) {
            int h = ((t & 15) + 16 * r) * 4;
            const float* s0 = src + (size_t)(2 * kp) * HID + h;
            float4 a  = *(const float4*)s0;
            float4 bb = *(const float4*)(s0 + HID);
            lds[h + 0][kp] = pack2(a.x, bb.x);
            lds[h + 1][kp] = pack2(a.y, bb.y);
            lds[h + 2][kp] = pack2(a.z, bb.z);
            lds[h + 3][kp] = pack2(a.w, bb.w);
        }
        __syncthreads();
        int swz = ((t & 15) >> 1) & 3;
        uint4* dst = (uint4*)(wD + (size_t)b2 * 8192 + t * 32);
#pragma unroll
        for (int c = 0; c < 4; ++c)
            dst[c] = *(const uint4*)&lds[t][(c ^ swz) * 4];
        return;
    }

    const int lane = tid & 63, w = tid >> 6;
    const int lr = lane & 15, lg = lane >> 4;
    const int rl = lane >> 2;
    const int sw8 = ((lane & 3) ^ ((lane >> 3) & 3)) * 8;   // A-source k pre-swizzle
    const int ksw = (lg ^ ((lr >> 1) & 3)) * 8;             // read-side swizzle

    const int xcd = blockIdx.x & 7, slot = blockIdx.x >> 3;  // 88 slots per xcd
    const int icnt = gcount[xcd], ib = gbase[xcd];

    for (int ii = slot; ii < icnt; ii += 88) {
        const int it = gu[ib + ii];
        const int e = it >> 10, fp = (it >> 6) & 15, tr = it & 63;
        const int seg0 = offs[e];
        const int rbase = tr * TM;
        const int nvalid = min(offs[e + 1] - seg0 - rbase, TM);
        const int row0 = seg0 + rbase;
        const int f0 = fp * 128;

        const bf16_t* aP[2];
#pragma unroll
        for (int i = 0; i < 2; ++i) {
            int r = w * 32 + i * 16 + rl;
            int tk = tok[row0 + min(r, nvalid - 1)];
            aP[i] = xb + (size_t)tk * HID + sw8;
        }
        const bf16_t* bT = wB + (size_t)(e * 11 + fp) * 64 * 8192 + lane * 8;

        f32x4 acc[8][4];
#pragma unroll
        for (int mi = 0; mi < 8; ++mi)
#pragma unroll
            for (int ni = 0; ni < 4; ++ni) acc[mi][ni] = (f32x4){0.f, 0.f, 0.f, 0.f};

        auto STAGE = [&](int b, int kt) {
            int k0 = kt * BK;
            bf16_t* A = smem + b * 4096;
            bf16_t* B = smem + 12288 + b * 8192;
            gll16(aP[0] + k0, A + (w * 2 + 0) * 512);
            gll16(aP[1] + k0, A + (w * 2 + 1) * 512);
            const bf16_t* bk = bT + (size_t)kt * 8192;
            gll16(bk + (w * 4 + 0) * 512, B + (w * 4 + 0) * 512);
            gll16(bk + (w * 4 + 1) * 512, B + (w * 4 + 1) * 512);
            gll16(bk + (w * 4 + 2) * 512, B + (w * 4 + 2) * 512);
            gll16(bk + (w * 4 + 3) * 512, B + (w * 4 + 3) * 512);
        };
        auto COMPUTE = [&](int b) {
            const bf16_t* A = smem + b * 4096;
            const bf16_t* B = smem + 12288 + b * 8192;
            bf16x8 bfr[4];
#pragma unroll
            for (int ni = 0; ni < 4; ++ni)
                bfr[ni] = *(const bf16x8*)&B[(w * 64 + ni * 16 + lr) * BK + ksw];
#pragma unroll
            for (int mi = 0; mi < 8; ++mi) {
                bf16x8 a = *(const bf16x8*)&A[(mi * 16 + lr) * BK + ksw];
#pragma unroll
                for (int ni = 0; ni < 4; ++ni)
                    acc[mi][ni] = __builtin_amdgcn_mfma_f32_16x16x32_bf16(a, bfr[ni], acc[mi][ni], 0, 0, 0);
            }
        };

        const int NK = HID / BK;   // 64
        STAGE(0, 0); STAGE(1, 1);
        int c0 = 0, c1 = 1, c2 = 2;
        for (int kt = 0; kt < NK - 1; ++kt) {
            SB0(); VMCNT6(); __builtin_amdgcn_s_barrier(); SB0();
            if (kt + 2 < NK) STAGE(c2, kt + 2);
            SB0();
            COMPUTE(c0);
            int t = c0; c0 = c1; c1 = c2; c2 = t;
        }
        SB0(); VMCNT0(); __builtin_amdgcn_s_barrier(); SB0();
        COMPUTE(c0);
        __syncthreads();

        // epilogue: up waves park u in LDS (bf16 [128][128]), gate waves combine
        if (w >= 2) {
#pragma unroll
            for (int mi = 0; mi < 8; ++mi)
#pragma unroll
                for (int ni = 0; ni < 4; ++ni)
#pragma unroll
                    for (int rr = 0; rr < 4; ++rr) {
                        int row = mi * 16 + lg * 4 + rr;
                        int col = (w - 2) * 64 + ni * 16 + lr;
                        smem[row * 128 + col] = (bf16_t)acc[mi][ni][rr];
                    }
        }
        __syncthreads();
        if (w < 2) {
#pragma unroll
            for (int mi = 0; mi < 8; ++mi)
#pragma unroll
                for (int ni = 0; ni < 4; ++ni)
#pragma unroll
                    for (int rr = 0; rr < 4; ++rr) {
                        int row = mi * 16 + lg * 4 + rr;
                        int col = w * 64 + ni * 16 + lr;
                        float g = acc[mi][ni][rr];
                        float u = (float)smem[row * 128 + col];
                        float h = (g / (1.f + __expf(-g))) * u;
                        if (row < nvalid)
                            h_buf[(size_t)(row0 + row) * FINT + f0 + col] = (bf16_t)h;
                    }
        }
        __syncthreads();
    }
}

// ======== down GEMM: 128 slots x 256 h-cols tile, tiled-B staging ========
__global__ __launch_bounds__(256, 2) void down3_kernel(
    const bf16_t* __restrict__ h_buf, const bf16_t* __restrict__ wD,
    const int* __restrict__ offs,
    const int* __restrict__ dbase, const int* __restrict__ dcount, const int* __restrict__ dn,
    bf16_t* __restrict__ y_buf)
{
    __shared__ bf16_t smem[36864];
    const int tid = threadIdx.x;
    const int lane = tid & 63, w = tid >> 6;
    const int lr = lane & 15, lg = lane >> 4;
    const int rl = lane >> 2;
    const int sw8 = ((lane & 3) ^ ((lane >> 3) & 3)) * 8;
    const int ksw = (lg ^ ((lr >> 1) & 3)) * 8;

    const int xcd = blockIdx.x & 7, slot = blockIdx.x >> 3;  // 64 slots per xcd
    const int icnt = dcount[xcd], ib = dbase[xcd];

    for (int ii = slot; ii < icnt; ii += 64) {
        const int it = dn[ib + ii];
        const int e = it >> 10, hp = (it >> 6) & 15, tr = it & 63;
        const int seg0 = offs[e];
        const int rbase = tr * TM;
        const int nvalid = min(offs[e + 1] - seg0 - rbase, TM);
        const int row0 = seg0 + rbase;
        const int h0 = hp * 256;

        const bf16_t* aP[2];
#pragma unroll
        for (int i = 0; i < 2; ++i) {
            int r = w * 32 + i * 16 + rl;
            aP[i] = h_buf + (size_t)(row0 + min(r, nvalid - 1)) * FINT + sw8;
        }
        const bf16_t* bT = wD + (size_t)(e * 8 + hp) * 44 * 8192 + lane * 8;

        f32x4 acc[8][4];
#pragma unroll
        for (int mi = 0; mi < 8; ++mi)
#pragma unroll
            for (int ni = 0; ni < 4; ++ni) acc[mi][ni] = (f32x4){0.f, 0.f, 0.f, 0.f};

        auto STAGE = [&](int b, int kt) {
            int k0 = kt * BK;
            bf16_t* A = smem + b * 4096;
            bf16_t* B = smem + 12288 + b * 8192;
            gll16(aP[0] + k0, A + (w * 2 + 0) * 512);
            gll16(aP[1] + k0, A + (w * 2 + 1) * 512);
            const bf16_t* bk = bT + (size_t)kt * 8192;
            gll16(bk + (w * 4 + 0) * 512, B + (w * 4 + 0) * 512);
            gll16(bk + (w * 4 + 1) * 512, B + (w * 4 + 1) * 512);
            gll16(bk + (w * 4 + 2) * 512, B + (w * 4 + 2) * 512);
            gll16(bk + (w * 4 + 3) * 512, B + (w * 4 + 3) * 512);
        };
        auto COMPUTE = [&](int b) {
            const bf16_t* A = smem + b * 4096;
            const bf16_t* B = smem + 12288 + b * 8192;
            bf16x8 bfr[4];
#pragma unroll
            for (int ni = 0; ni < 4; ++ni)
                bfr[ni] = *(const bf16x8*)&B[(w * 64 + ni * 16 + lr) * BK + ksw];
#pragma unroll
            for (int mi = 0; mi < 8; ++mi) {
                bf16x8 a = *(const bf16x8*)&A[(mi * 16 + lr) * BK + ksw];
#pragma unroll
                for (int ni = 0; ni < 4; ++ni)
                    acc[mi][ni] = __builtin_amdgcn_mfma_f32_16x16x32_bf16(a, bfr[ni], acc[mi][ni], 0, 0, 0);
            }
        };

        const int NK = FINT / BK;  // 44
        STAGE(0, 0); STAGE(1, 1);
        int c0 = 0, c1 = 1, c2 = 2;
        for (int kt = 0; kt < NK - 1; ++kt) {
            SB0(); VMCNT6(); __builtin_amdgcn_s_barrier(); SB0();
            if (kt + 2 < NK) STAGE(c2, kt + 2);
            SB0();
            COMPUTE(c0);
            int t = c0; c0 = c1; c1 = c2; c2 = t;
        }
        SB0(); VMCNT0(); __builtin_amdgcn_s_barrier(); SB0();
        COMPUTE(c0);

#pragma unroll
        for (int mi = 0; mi < 8; ++mi)
#pragma unroll
            for (int ni = 0; ni < 4; ++ni)
#pragma unroll
                for (int rr = 0; rr < 4; ++rr) {
                    int row = mi * 16 + lg * 4 + rr;
                    int col = w * 64 + ni * 16 + lr;
                    if (row < nvalid)
                        y_buf[(size_t)(row0 + row) * HID + h0 + col] = (bf16_t)acc[mi][ni][rr];
                }
        __syncthreads();
    }
}

// ---------------- combine: out[t] = w0*y[s0] + w1*y[s1] ----------------
__global__ __launch_bounds__(256) void combine_kernel(
    const bf16_t* __restrict__ y, const int* __restrict__ slot_of,
    const float* __restrict__ topk_w, float* __restrict__ out, int T)
{
    int t = blockIdx.x;
    int tid = threadIdx.x;
    int s0 = slot_of[t * 2], s1 = slot_of[t * 2 + 1];
    float w0 = topk_w[t * 2], w1 = topk_w[t * 2 + 1];
    const bf16x8* y0 = (const bf16x8*)(y + (size_t)s0 * HID);
    const bf16x8* y1 = (const bf16x8*)(y + (size_t)s1 * HID);
    bf16x8 v0 = y0[tid], v1 = y1[tid];
    float* op = out + (size_t)t * HID + tid * 8;
#pragma unroll
    for (int j = 0; j < 8; ++j)
        op[j] = w0 * (float)v0[j] + w1 * (float)v1[j];
}

extern "C" void kernel_launch(void* const* d_in, const int* in_sizes, int n_in,
                              void* d_out, int out_size, void* d_ws, size_t ws_size,
                              hipStream_t stream)
{
    const float* x  = (const float*)d_in[0];
    const float* gw = (const float*)d_in[1];
    const float* wg = (const float*)d_in[2];
    const float* wu = (const float*)d_in[3];
    const float* wd = (const float*)d_in[4];
    float* out = (float*)d_out;
    int T = in_sizes[0] / HID;     // 4096
    int S2 = 2 * T;

    char* base = (char*)d_ws;
    int* cnt     = (int*)base;
    int* fill    = cnt + 8;
    int* offs    = cnt + 16;
    int* gbase   = cnt + 32;
    int* gcount  = cnt + 40;
    int* dbase   = cnt + 48;
    int* dcount  = cnt + 56;
    int* gu      = cnt + 64;
    int* dnl     = cnt + 1088;
    int* topk_id = cnt + 1856;
    float* topk_w = (float*)(topk_id + S2);
    int* tok     = (int*)(topk_w + S2);
    int* slot_of = tok + S2 + 256;
    size_t small_end = (size_t)((char*)(slot_of + S2) - base);
    size_t cur = (small_end + 255) & ~(size_t)255;
    auto take = [&](size_t bytes) -> size_t {
        size_t o = cur; cur += bytes; cur = (cur + 255) & ~(size_t)255; return o;
    };
    size_t o_xb = take((size_t)T * HID * 2);
    size_t o_wB = take((size_t)NG_GU * 8192 * 2);
    size_t o_wD = take((size_t)NG_DN * 8192 * 2);
    size_t o_h  = take((size_t)(S2 + 256) * FINT * 2);
    size_t o_y  = take((size_t)(S2 + 256) * HID * 2);
    (void)ws_size;

    bf16_t* xb    = (bf16_t*)(base + o_xb);
    bf16_t* wB    = (bf16_t*)(base + o_wB);
    bf16_t* wD    = (bf16_t*)(base + o_wD);
    bf16_t* h_buf = (bf16_t*)(base + o_h);
    bf16_t* y_buf = (bf16_t*)(base + o_y);

    hipMemsetAsync(base, 0, 64, stream);   // cnt + fill

    int RB = T / 4;                        // 1024 router blocks
    int gridPrep = RB + NG_GU;             // 1024 + 5632
    prep_kernel<<<gridPrep, 256, 0, stream>>>(x, gw, cnt, topk_id, topk_w, xb, T,
                                              wg, wu, wB);
    offsets_kernel<<<1, 64, 0, stream>>>(cnt, offs, gbase, gcount, dbase, dcount, gu, dnl);
    scatter_kernel<<<(T + 255) / 256, 256, 0, stream>>>(topk_id, offs, fill, tok, slot_of, T);

    gateup3_kernel<<<GU_GRID + NG_DN, 256, 0, stream>>>(xb, wB, offs, tok, gbase, gcount, gu,
                                                        h_buf, wd, wD);
    down3_kernel<<<512, 256, 0, stream>>>(h_buf, wD, offs, dbase, dcount, dnl, y_buf);
    combine_kernel<<<T, 256, 0, stream>>>(y_buf, slot_of, topk_w, out, T);
}